// Round 4
// baseline (4066.233 us; speedup 1.0000x reference)
//
#include <hip/hip_runtime.h>
#include <hip/hip_bf16.h>

// ---- problem constants ----
#define SEM_DIM   256
#define CODEBOOK  8192
#define B_        8
#define T_        4096
#define D_        292
#define NCH       37
#define EPSV      1e-5f
#define NS        2
#define DELTA     0.05f
#define CAP       12

typedef unsigned short u16;
typedef float v4f __attribute__((ext_vector_type(4)));
typedef short v8s __attribute__((ext_vector_type(8)));

constexpr int ROWS = B_ * T_;                 // 32768
// d_out used as flat scratch until final writers run. Aliasing order audited:
// Xh/Xl dead after gemm_emit; Eh/El dead after gemm_emit; e2 dead after
// finalize; v1/cnt/cand dead after finalize. finalize/fsq/gather then
// overwrite everything (full codes+recon coverage each launch).
constexpr size_t OFF_XH   = 0;                // u16[32768*256] = 4,194,304 fl
constexpr size_t OFF_XL   = 4194304;
constexpr size_t OFF_EH   = 8388608;          // u16[8192*256] = 1,048,576 fl
constexpr size_t OFF_EL   = 9437184;
constexpr size_t OFF_E2   = 10485760;         // f32[8192]
constexpr size_t OFF_V1   = 10493952;         // u32[32768] (enc-mapped min)
constexpr size_t OFF_CNT  = 10526720;         // i32[32768]
constexpr size_t OFF_CAND = 10559488;         // u16[32768*CAP] = 196608 fl -> end 10756096
constexpr size_t RECON_OFF = 1212416;

__device__ __forceinline__ u16 bf16bits(float v) {
    __hip_bfloat16 h = __float2bfloat16(v);
    return *(u16*)&h;
}
__device__ __forceinline__ float bf16val(u16 b) {
    __hip_bfloat16 h; *(u16*)&h = b; return __bfloat162float(h);
}
// monotone float<->uint map for atomicMin on float scores
__device__ __forceinline__ unsigned enc_f(float f) {
    unsigned u = __float_as_uint(f);
    return (u & 0x80000000u) ? ~u : (u | 0x80000000u);
}
__device__ __forceinline__ float dec_f(unsigned k) {
    unsigned u = (k & 0x80000000u) ? (k & 0x7FFFFFFFu) : ~k;
    return __uint_as_float(u);
}

// ---- kernel 0: init v1/cnt ----
__global__ __launch_bounds__(256) void init_kernel(unsigned* __restrict__ v1u,
                                                   int* __restrict__ cnt)
{
    int r = blockIdx.x * 256 + threadIdx.x;
    v1u[r] = 0xFFFFFFFFu;
    cnt[r] = 0;
}

// ---- kernel 1: Eh/El = split-bf16(es/max(cu,eps)); e2 = sum(emb^2) ----
__global__ __launch_bounds__(256) void prep_emb_kernel(
    const float* __restrict__ es, const float* __restrict__ cu,
    u16* __restrict__ Eh, u16* __restrict__ El, float* __restrict__ e2)
{
    int c = blockIdx.x;
    int d = threadIdx.x;
    float denom = fmaxf(cu[c], EPSV);
    float v = es[(size_t)c * SEM_DIM + d] / denom;   // IEEE div, matches ref
    u16 hb = bf16bits(v);
    float rr = v - bf16val(hb);
    Eh[(size_t)c * SEM_DIM + d] = hb;
    El[(size_t)c * SEM_DIM + d] = bf16bits(rr);

    float s = v * v;
    #pragma unroll
    for (int m = 32; m >= 1; m >>= 1) s += __shfl_xor(s, m);
    __shared__ float red[4];
    int lane = threadIdx.x & 63, w = threadIdx.x >> 6;
    if (lane == 0) red[w] = s;
    __syncthreads();
    if (threadIdx.x == 0)
        e2[c] = red[0] + red[1] + red[2] + red[3];
}

// ---- kernel 2: transpose-cast x[:, :256, :] -> Xh, Xl row-major (m,k) ----
__global__ __launch_bounds__(256) void prep_x_kernel(
    const float* __restrict__ x, u16* __restrict__ Xh, u16* __restrict__ Xl)
{
    __shared__ float tile[64][65];
    int bidx = blockIdx.x;            // 8 * 64 * 4
    int dc = bidx & 3;
    int tc = (bidx >> 2) & 63;
    int b  = bidx >> 8;
    int d0 = dc * 64, t0 = tc * 64;
    int tx = threadIdx.x & 63;
    int dq = threadIdx.x >> 6;
    #pragma unroll
    for (int i = 0; i < 16; i++) {
        int d = dq * 16 + i;
        tile[d][tx] = x[((size_t)b * D_ + d0 + d) * T_ + t0 + tx];
    }
    __syncthreads();
    #pragma unroll
    for (int j = 0; j < 2; j++) {
        int lin = threadIdx.x * 2 + j;      // 0..511
        int tr  = lin >> 3;
        int ch  = lin & 7;
        unsigned hw[4], lw[4];
        #pragma unroll
        for (int p = 0; p < 4; p++) {
            float v0 = tile[ch * 8 + p * 2 + 0][tr];
            float v1 = tile[ch * 8 + p * 2 + 1][tr];
            u16 h0 = bf16bits(v0), h1 = bf16bits(v1);
            u16 l0 = bf16bits(v0 - bf16val(h0));
            u16 l1 = bf16bits(v1 - bf16val(h1));
            hw[p] = (unsigned)h0 | ((unsigned)h1 << 16);
            lw[p] = (unsigned)l0 | ((unsigned)l1 << 16);
        }
        size_t off = ((size_t)b * T_ + t0 + tr) * SEM_DIM + d0 + ch * 8;
        *(uint4*)(Xh + off) = make_uint4(hw[0], hw[1], hw[2], hw[3]);
        *(uint4*)(Xl + off) = make_uint4(lw[0], lw[1], lw[2], lw[3]);
    }
}

// ---- kernel 3: MFMA GEMM (3-term split-bf16). EMIT=false: per-row approx
// min via atomicMin. EMIT=true: emit all codes with s <= v1+DELTA. ----
#define GBM 128
#define GBN 128
#define GBK 64
#define LDP 72

template<bool EMIT>
__global__ __launch_bounds__(256) void gemm_kernel(
    const u16* __restrict__ Xh, const u16* __restrict__ Xl,
    const u16* __restrict__ Eh, const u16* __restrict__ El,
    const float* __restrict__ e2,
    unsigned* __restrict__ v1u, int* __restrict__ cnt, u16* __restrict__ cand)
{
    __shared__ u16 As[GBM * LDP];
    __shared__ u16 Bs[GBN * LDP];
    int tid  = threadIdx.x;
    int lane = tid & 63, wid = tid >> 6;
    int wm = wid >> 1, wn = wid & 1;
    int m0 = blockIdx.x * GBM;
    int split = blockIdx.y;
    int cbase = split * (CODEBOOK / NS);

    int lrow = tid >> 3;                    // 0..31
    int lch  = tid & 7;
    int wch  = (lch ^ (lrow & 7)) * 8;      // swizzled chunk (u16 units)

    float vmin[16];
    float tau[16];
    #pragma unroll
    for (int s = 0; s < 16; s++) vmin[s] = 3.4e38f;
    if (EMIT) {
        #pragma unroll
        for (int s = 0; s < 16; s++) {
            int row = m0 + wm * 64 + (s >> 2) * 16 + (lane >> 4) * 4 + (s & 3);
            tau[s] = dec_f(v1u[row]) + DELTA;
        }
    }

    const int NIT = (CODEBOOK / NS) / GBN * 12;
    uint4 pa[4], pb[4];

    auto load_it = [&](int it) {
        int st  = it % 12;
        int nt  = it / 12;
        int seg = st >> 2;                  // 0: Xh*Eh, 1: Xh*El, 2: Xl*Eh
        int ko  = (st & 3) * GBK;
        int n0  = cbase + nt * GBN;
        const u16* Asrc = (seg == 2) ? Xl : Xh;
        const u16* Bsrc = (seg == 1) ? El : Eh;
        #pragma unroll
        for (int q = 0; q < 4; q++) {
            int row = q * 32 + lrow;
            pa[q] = *(const uint4*)(Asrc + (size_t)(m0 + row) * SEM_DIM + ko + lch * 8);
            pb[q] = *(const uint4*)(Bsrc + (size_t)(n0 + row) * SEM_DIM + ko + lch * 8);
        }
    };

    load_it(0);

    v4f acc[4][4];

    for (int it = 0; it < NIT; ++it) {
        int st = it % 12;
        int n0 = cbase + (it / 12) * GBN;
        if (st == 0) {
            #pragma unroll
            for (int mf = 0; mf < 4; mf++)
                #pragma unroll
                for (int nf = 0; nf < 4; nf++)
                    acc[mf][nf] = (v4f){0.f, 0.f, 0.f, 0.f};
        }
        __syncthreads();
        #pragma unroll
        for (int q = 0; q < 4; q++) {
            int row = q * 32 + lrow;
            *(uint4*)&As[row * LDP + wch] = pa[q];
            *(uint4*)&Bs[row * LDP + wch] = pb[q];
        }
        __syncthreads();
        if (it + 1 < NIT) load_it(it + 1);

        #pragma unroll
        for (int kk = 0; kk < 2; ++kk) {
            v8s af[4], bfr[4];
            #pragma unroll
            for (int mf = 0; mf < 4; mf++) {
                int r  = wm * 64 + mf * 16 + (lane & 15);
                int ch = kk * 4 + (lane >> 4);
                af[mf] = *(const v8s*)&As[r * LDP + ((ch ^ (r & 7)) * 8)];
            }
            #pragma unroll
            for (int nf = 0; nf < 4; nf++) {
                int r  = wn * 64 + nf * 16 + (lane & 15);
                int ch = kk * 4 + (lane >> 4);
                bfr[nf] = *(const v8s*)&Bs[r * LDP + ((ch ^ (r & 7)) * 8)];
            }
            #pragma unroll
            for (int mf = 0; mf < 4; mf++)
                #pragma unroll
                for (int nf = 0; nf < 4; nf++)
                    acc[mf][nf] = __builtin_amdgcn_mfma_f32_16x16x32_bf16(
                        af[mf], bfr[nf], acc[mf][nf], 0, 0, 0);
        }

        if (st == 11) {
            float e2v[4]; int cc[4];
            #pragma unroll
            for (int nf = 0; nf < 4; nf++) {
                cc[nf]  = n0 + wn * 64 + nf * 16 + (lane & 15);
                e2v[nf] = e2[cc[nf]];
            }
            #pragma unroll
            for (int mf = 0; mf < 4; mf++)
                #pragma unroll
                for (int r = 0; r < 4; r++) {
                    int slot = mf * 4 + r;
                    #pragma unroll
                    for (int nf = 0; nf < 4; nf++) {
                        float s = fmaf(-2.0f, acc[mf][nf][r], e2v[nf]);
                        if (!EMIT) {
                            vmin[slot] = fminf(vmin[slot], s);
                        } else if (s <= tau[slot]) {
                            int row = m0 + wm * 64 + mf * 16 + (lane >> 4) * 4 + r;
                            int p = atomicAdd(&cnt[row], 1);
                            if (p < CAP) cand[(size_t)row * CAP + p] = (u16)cc[nf];
                        }
                    }
                }
        }
    }

    if (!EMIT) {
        #pragma unroll
        for (int slot = 0; slot < 16; slot++) {
            float v = vmin[slot];
            #pragma unroll
            for (int m = 1; m < 16; m <<= 1)
                v = fminf(v, __shfl_xor(v, m));
            if ((lane & 15) == 0) {
                int row = m0 + wm * 64 + (slot >> 2) * 16 + (lane >> 4) * 4 + (slot & 3);
                atomicMin(&v1u[row], enc_f(v));
            }
        }
    }
}

// ---- kernel 4: exact fp32 rescore of candidates (bit-matches reference path) ----
__global__ __launch_bounds__(256) void finalize_kernel(
    const int* __restrict__ cnt, const u16* __restrict__ cand,
    const float* __restrict__ x, const float* __restrict__ es,
    const float* __restrict__ cu, const float* __restrict__ e2,
    float* __restrict__ out)
{
    int r = blockIdx.x * 256 + threadIdx.x;
    int n = cnt[r]; if (n > CAP) n = CAP;
    int b = r >> 12, t = r & 4095;
    float best_s = 3.4e38f; int best_i = 0;
    for (int p = 0; p < n; p++) {
        int c = cand[(size_t)r * CAP + p];
        float den = fmaxf(cu[c], EPSV);
        float acc = 0.f;
        for (int k = 0; k < SEM_DIM; k++) {
            float xv = x[((size_t)b * D_ + k) * T_ + t];
            acc = fmaf(xv, es[(size_t)c * SEM_DIM + k] / den, acc);
        }
        float s = e2[c] - 2.0f * acc;
        if (s < best_s || (s == best_s && c < best_i)) { best_s = s; best_i = c; }
    }
    out[(size_t)b * NCH * T_ + t] = (float)best_i;
}

// ---- kernel 5: FSQ codes + ac recon ----
__global__ __launch_bounds__(256) void fsq_kernel(
    const float* __restrict__ x, float* __restrict__ out)
{
    int e = blockIdx.x * 256 + threadIdx.x;
    int t = e & 4095;
    int rest = e >> 12;
    int j = rest % 36;
    int b = rest / 36;
    float v = x[(size_t)b * D_ * T_ + (size_t)(SEM_DIM + j) * T_ + t];
    float a = tanhf(v);
    float code = rintf((a + 1.0f) * 10.0f);
    out[(size_t)b * NCH * T_ + (size_t)(1 + j) * T_ + t] = code;
    out[RECON_OFF + (size_t)b * D_ * T_ + (size_t)(SEM_DIM + j) * T_ + t]
        = code * 0.1f - 1.0f;
}

// ---- kernel 6: recon sem gather ----
__global__ __launch_bounds__(256) void gather_kernel(
    const float* __restrict__ es, const float* __restrict__ cu,
    const float* __restrict__ codes, float* __restrict__ out)
{
    int bid = blockIdx.x;
    int b  = bid >> 6;
    int tc = bid & 63;
    int t  = tc * 64 + (threadIdx.x & 63);
    int w  = threadIdx.x >> 6;

    int c = (int)codes[(size_t)b * NCH * T_ + t];
    float denom = fmaxf(cu[c], EPSV);
    const float* erow = es + (size_t)c * SEM_DIM;
    float* orow = out + RECON_OFF + (size_t)b * D_ * T_ + t;

    #pragma unroll
    for (int i = 0; i < 16; i++) {
        int d = w * 64 + i * 4;
        float4 ev = *(const float4*)(erow + d);
        orow[(size_t)(d + 0) * T_] = ev.x / denom;
        orow[(size_t)(d + 1) * T_] = ev.y / denom;
        orow[(size_t)(d + 2) * T_] = ev.z / denom;
        orow[(size_t)(d + 3) * T_] = ev.w / denom;
    }
}

extern "C" void kernel_launch(void* const* d_in, const int* in_sizes, int n_in,
                              void* d_out, int out_size, void* d_ws, size_t ws_size,
                              hipStream_t stream)
{
    const float* x  = (const float*)d_in[0];
    const float* es = (const float*)d_in[1];
    const float* cu = (const float*)d_in[2];
    float* out = (float*)d_out;

    u16*      Xh   = (u16*)(out + OFF_XH);
    u16*      Xl   = (u16*)(out + OFF_XL);
    u16*      Eh   = (u16*)(out + OFF_EH);
    u16*      El   = (u16*)(out + OFF_EL);
    float*    e2   = out + OFF_E2;
    unsigned* v1u  = (unsigned*)(out + OFF_V1);
    int*      cnt  = (int*)(out + OFF_CNT);
    u16*      cand = (u16*)(out + OFF_CAND);

    init_kernel<<<ROWS / 256, 256, 0, stream>>>(v1u, cnt);
    prep_emb_kernel<<<CODEBOOK, 256, 0, stream>>>(es, cu, Eh, El, e2);
    prep_x_kernel<<<B_ * 64 * 4, 256, 0, stream>>>(x, Xh, Xl);

    dim3 g(ROWS / GBM, NS);
    gemm_kernel<false><<<g, 256, 0, stream>>>(Xh, Xl, Eh, El, e2, v1u, cnt, cand);
    gemm_kernel<true ><<<g, 256, 0, stream>>>(Xh, Xl, Eh, El, e2, v1u, cnt, cand);

    finalize_kernel<<<ROWS / 256, 256, 0, stream>>>(cnt, cand, x, es, cu, e2, out);

    fsq_kernel<<<(B_ * 36 * T_) / 256, 256, 0, stream>>>(x, out);

    gather_kernel<<<B_ * (T_ / 64), 256, 0, stream>>>(es, cu, out, out);
}

// Round 5
// 1494.011 us; speedup vs baseline: 2.7217x; 2.7217x over previous
//
#include <hip/hip_runtime.h>
#include <hip/hip_bf16.h>

// ---- problem constants ----
#define SEM_DIM   256
#define CODEBOOK  8192
#define B_        8
#define T_        4096
#define D_        292
#define NCH       37
#define EPSV      1e-5f
#define NS        2
#define DELTA     0.03f
#define CAPMAX    24
#define CAPFALL   11

typedef unsigned short u16;
typedef unsigned long long u64;
typedef float v4f __attribute__((ext_vector_type(4)));
typedef short v8s __attribute__((ext_vector_type(8)));

constexpr int ROWS = B_ * T_;                 // 32768
// d_out used as flat scratch until the final writers run. Order:
// gemm consumes Xh/Xl/Eh/El; finalize consumes e2/amin/cnt/cand; then
// finalize/fsq/gather overwrite everything (full codes+recon coverage).
constexpr size_t OFF_XH   = 0;                // u16[32768*256] = 4,194,304 fl
constexpr size_t OFF_XL   = 4194304;
constexpr size_t OFF_EH   = 8388608;          // u16[8192*256] = 1,048,576 fl
constexpr size_t OFF_EL   = 9437184;
constexpr size_t OFF_E2   = 10485760;         // f32[8192] -> 10,493,952
constexpr size_t OFF_AMIN = 10493952;         // u64[32768] = 65,536 fl -> 10,559,488
constexpr size_t OFF_CNT  = 10559488;         // i32[32768] -> 10,592,256
constexpr size_t OFF_CAND = 10592256;         // u16[32768*11] = 180,224 fl -> 10,772,480 (<=10,780,672)
constexpr size_t RECON_OFF = 1212416;

__device__ __forceinline__ u16 bf16bits(float v) {
    __hip_bfloat16 h = __float2bfloat16(v);
    return *(u16*)&h;
}
__device__ __forceinline__ float bf16val(u16 b) {
    __hip_bfloat16 h; *(u16*)&h = b; return __bfloat162float(h);
}
__device__ __forceinline__ unsigned enc_f(float f) {
    unsigned u = __float_as_uint(f);
    return (u & 0x80000000u) ? ~u : (u | 0x80000000u);
}

// ---- kernel 0: init amin/cnt ----
__global__ __launch_bounds__(256) void init_kernel(u64* __restrict__ amin,
                                                   int* __restrict__ cnt)
{
    int r = blockIdx.x * 256 + threadIdx.x;
    amin[r] = 0xFFFFFFFFFFFFFFFFull;
    cnt[r] = 0;
}

// ---- kernel 1: Eh/El = split-bf16(es/max(cu,eps)); e2 = sum(emb^2) ----
__global__ __launch_bounds__(256) void prep_emb_kernel(
    const float* __restrict__ es, const float* __restrict__ cu,
    u16* __restrict__ Eh, u16* __restrict__ El, float* __restrict__ e2)
{
    int c = blockIdx.x;
    int d = threadIdx.x;
    float denom = fmaxf(cu[c], EPSV);
    float v = es[(size_t)c * SEM_DIM + d] / denom;   // IEEE div, matches ref
    u16 hb = bf16bits(v);
    float rr = v - bf16val(hb);
    Eh[(size_t)c * SEM_DIM + d] = hb;
    El[(size_t)c * SEM_DIM + d] = bf16bits(rr);

    float s = v * v;
    #pragma unroll
    for (int m = 32; m >= 1; m >>= 1) s += __shfl_xor(s, m);
    __shared__ float red[4];
    int lane = threadIdx.x & 63, w = threadIdx.x >> 6;
    if (lane == 0) red[w] = s;
    __syncthreads();
    if (threadIdx.x == 0)
        e2[c] = red[0] + red[1] + red[2] + red[3];
}

// ---- kernel 2: transpose-cast x[:, :256, :] -> Xh, Xl row-major (m,k) ----
__global__ __launch_bounds__(256) void prep_x_kernel(
    const float* __restrict__ x, u16* __restrict__ Xh, u16* __restrict__ Xl)
{
    __shared__ float tile[64][65];
    int bidx = blockIdx.x;            // 8 * 64 * 4
    int dc = bidx & 3;
    int tc = (bidx >> 2) & 63;
    int b  = bidx >> 8;
    int d0 = dc * 64, t0 = tc * 64;
    int tx = threadIdx.x & 63;
    int dq = threadIdx.x >> 6;
    #pragma unroll
    for (int i = 0; i < 16; i++) {
        int d = dq * 16 + i;
        tile[d][tx] = x[((size_t)b * D_ + d0 + d) * T_ + t0 + tx];
    }
    __syncthreads();
    #pragma unroll
    for (int j = 0; j < 2; j++) {
        int lin = threadIdx.x * 2 + j;      // 0..511
        int tr  = lin >> 3;
        int ch  = lin & 7;
        unsigned hw[4], lw[4];
        #pragma unroll
        for (int p = 0; p < 4; p++) {
            float v0 = tile[ch * 8 + p * 2 + 0][tr];
            float v1 = tile[ch * 8 + p * 2 + 1][tr];
            u16 h0 = bf16bits(v0), h1 = bf16bits(v1);
            u16 l0 = bf16bits(v0 - bf16val(h0));
            u16 l1 = bf16bits(v1 - bf16val(h1));
            hw[p] = (unsigned)h0 | ((unsigned)h1 << 16);
            lw[p] = (unsigned)l0 | ((unsigned)l1 << 16);
        }
        size_t off = ((size_t)b * T_ + t0 + tr) * SEM_DIM + d0 + ch * 8;
        *(uint4*)(Xh + off) = make_uint4(hw[0], hw[1], hw[2], hw[3]);
        *(uint4*)(Xl + off) = make_uint4(lw[0], lw[1], lw[2], lw[3]);
    }
}

// ---- kernel 3: single-pass MFMA GEMM (A in VGPR, B streamed via LDS) +
//      running-min threshold emission + per-row approx-argmin guard ----
#define GBM 128
#define GBN 64
#define NTILES (CODEBOOK / NS / GBN)          // 64
#define TSTEPS (NTILES * 4)                   // 256 (64-k per step)

__global__ __launch_bounds__(512, 2) void gemm_emit_kernel(
    const u16* __restrict__ Xh, const u16* __restrict__ Xl,
    const u16* __restrict__ Eh, const u16* __restrict__ El,
    const float* __restrict__ e2,
    u64* __restrict__ amin, int* __restrict__ cnt, u16* __restrict__ cand,
    int cap)
{
    __shared__ u16 Bs[2][2][GBN * 64];        // [parity][Eh/El][64n x 64k] = 32 KB
    int tid  = threadIdx.x;
    int lane = tid & 63, wid = tid >> 6;
    int wm = wid >> 1, wn = wid & 1;          // 4 x 2 waves; wave tile 32m x 32n
    int l15 = lane & 15, l4 = lane >> 4;
    int m0 = blockIdx.x * GBM;
    int cbase = blockIdx.y * (CODEBOOK / NS);

    // A fragments resident in VGPRs: [mf][kk] over all K=256
    v8s aXh[2][8], aXl[2][8];
    #pragma unroll
    for (int mf = 0; mf < 2; mf++) {
        int row = m0 + wm * 32 + mf * 16 + l15;
        #pragma unroll
        for (int kk = 0; kk < 8; kk++) {
            size_t off = (size_t)row * SEM_DIM + (kk * 4 + l4) * 8;
            aXh[mf][kk] = *(const v8s*)(Xh + off);
            aXl[mf][kk] = *(const v8s*)(Xl + off);
        }
    }

    // staging role: tid<256 -> Eh, else El; two 16B slots per thread
    const u16* Msrc = (tid < 256) ? Eh : El;
    int mi  = (tid < 256) ? 0 : 1;
    int u   = tid & 255;
    int n_a = u >> 3,        c_a = u & 7;      // slot u
    int n_b = 32 + (u >> 3), c_b = u & 7;      // slot u+256
    uint4 sA, sB;

    auto load_stage = [&](int s) {
        int nt = s >> 2, sub = s & 3;
        int n0 = cbase + nt * GBN, k0 = sub * 64;
        sA = *(const uint4*)(Msrc + (size_t)(n0 + n_a) * SEM_DIM + k0 + c_a * 8);
        sB = *(const uint4*)(Msrc + (size_t)(n0 + n_b) * SEM_DIM + k0 + c_b * 8);
    };

    v4f acc[2][2];
    #pragma unroll
    for (int mf = 0; mf < 2; mf++)
        #pragma unroll
        for (int nf = 0; nf < 2; nf++)
            acc[mf][nf] = (v4f){0.f, 0.f, 0.f, 0.f};

    float rv[8]; int ri[8];
    #pragma unroll
    for (int s = 0; s < 8; s++) { rv[s] = 3.4e38f; ri[s] = 0; }

    load_stage(0);

    for (int s = 0; s < TSTEPS; ++s) {
        int p = s & 1;
        // write staged data for step s (buffer parity p; prior compute used !p)
        *(uint4*)&Bs[p][mi][n_a * 64 + ((c_a ^ (n_a & 7)) * 8)] = sA;
        *(uint4*)&Bs[p][mi][n_b * 64 + ((c_b ^ (n_b & 7)) * 8)] = sB;
        __syncthreads();
        if (s + 1 < TSTEPS) load_stage(s + 1);   // overlap HBM/L2 with MFMAs

        int sub = s & 3;
        #pragma unroll
        for (int w = 0; w < 2; w++) {
            v8s bh[2], bl[2];
            #pragma unroll
            for (int nf = 0; nf < 2; nf++) {
                int n = wn * 32 + nf * 16 + l15;
                int c = w * 4 + l4;
                int e = n * 64 + ((c ^ (n & 7)) * 8);
                bh[nf] = *(const v8s*)&Bs[p][0][e];
                bl[nf] = *(const v8s*)&Bs[p][1][e];
            }
            #pragma unroll
            for (int mf = 0; mf < 2; mf++)
                #pragma unroll
                for (int nf = 0; nf < 2; nf++) {
                    int kkg = sub * 2 + w;
                    acc[mf][nf] = __builtin_amdgcn_mfma_f32_16x16x32_bf16(
                        aXh[mf][kkg], bh[nf], acc[mf][nf], 0, 0, 0);
                    acc[mf][nf] = __builtin_amdgcn_mfma_f32_16x16x32_bf16(
                        aXl[mf][kkg], bh[nf], acc[mf][nf], 0, 0, 0);
                    acc[mf][nf] = __builtin_amdgcn_mfma_f32_16x16x32_bf16(
                        aXh[mf][kkg], bl[nf], acc[mf][nf], 0, 0, 0);
                }
        }

        if (sub == 3) {
            // epilogue for n-tile nt: scores, running-min, threshold emit
            int nt = s >> 2;
            int n0 = cbase + nt * GBN;
            int cc0 = n0 + wn * 32 + l15, cc1 = cc0 + 16;
            float e20 = e2[cc0], e21 = e2[cc1];
            #pragma unroll
            for (int mf = 0; mf < 2; mf++)
                #pragma unroll
                for (int r = 0; r < 4; r++) {
                    int slot = mf * 4 + r;
                    float s0 = fmaf(-2.0f, acc[mf][0][r], e20);
                    float s1 = fmaf(-2.0f, acc[mf][1][r], e21);
                    float v; int i;
                    if (s1 < s0) { v = s1; i = cc1; } else { v = s0; i = cc0; }
                    #pragma unroll
                    for (int m = 1; m < 16; m <<= 1) {
                        float ov = __shfl_xor(v, m);
                        int   oi = __shfl_xor(i, m);
                        if (ov < v || (ov == v && oi < i)) { v = ov; i = oi; }
                    }
                    if (v < rv[slot] || (v == rv[slot] && i < ri[slot])) {
                        rv[slot] = v; ri[slot] = i;
                    }
                    float thr = rv[slot] + DELTA;
                    int row = m0 + wm * 32 + mf * 16 + l4 * 4 + r;
                    if (s0 <= thr) {
                        int q = atomicAdd(&cnt[row], 1);
                        if (q < cap) cand[(size_t)row * cap + q] = (u16)cc0;
                    }
                    if (s1 <= thr) {
                        int q = atomicAdd(&cnt[row], 1);
                        if (q < cap) cand[(size_t)row * cap + q] = (u16)cc1;
                    }
                }
            #pragma unroll
            for (int mf = 0; mf < 2; mf++)
                #pragma unroll
                for (int nf = 0; nf < 2; nf++)
                    acc[mf][nf] = (v4f){0.f, 0.f, 0.f, 0.f};
        }
    }

    // per-row approx-argmin guard (overflow safety)
    #pragma unroll
    for (int slot = 0; slot < 8; slot++) {
        if (l15 == 0) {
            int row = m0 + wm * 32 + (slot >> 2) * 16 + l4 * 4 + (slot & 3);
            u64 key = ((u64)enc_f(rv[slot]) << 32) | (unsigned)ri[slot];
            atomicMin(&amin[row], key);
        }
    }
}

// ---- kernel 4: exact fp32 rescore of candidates, wave-per-row ----
__global__ __launch_bounds__(256) void finalize_kernel(
    const int* __restrict__ cnt, const u16* __restrict__ cand,
    const u64* __restrict__ amin,
    const float* __restrict__ x, const float* __restrict__ es,
    const float* __restrict__ cu, const float* __restrict__ e2,
    float* __restrict__ out, int cap)
{
    int r = (blockIdx.x * 256 + threadIdx.x) >> 6;   // one wave per row
    int lane = threadIdx.x & 63;
    int b = r >> 12, t = r & 4095;

    float xv[4];
    #pragma unroll
    for (int j = 0; j < 4; j++)
        xv[j] = x[((size_t)b * D_ + lane + j * 64) * T_ + t];

    int n = cnt[r]; if (n > cap) n = cap;
    int ai = (int)(unsigned)(amin[r] & 0xFFFFFFFFu);

    float best_s = 3.4e38f; int best_i = 0x7FFFFFFF;
    for (int p = 0; p <= n; p++) {
        int c = (p < n) ? (int)cand[(size_t)r * cap + p] : ai;
        float den = fmaxf(cu[c], EPSV);
        float partial = 0.f;
        #pragma unroll
        for (int j = 0; j < 4; j++)
            partial = fmaf(xv[j], es[(size_t)c * SEM_DIM + lane + j * 64] / den, partial);
        #pragma unroll
        for (int m = 32; m >= 1; m >>= 1) partial += __shfl_xor(partial, m);
        float sc = e2[c] - 2.0f * partial;
        if (sc < best_s || (sc == best_s && c < best_i)) { best_s = sc; best_i = c; }
    }
    if (lane == 0) out[(size_t)b * NCH * T_ + t] = (float)best_i;
}

// ---- kernel 5: FSQ codes + ac recon ----
__global__ __launch_bounds__(256) void fsq_kernel(
    const float* __restrict__ x, float* __restrict__ out)
{
    int e = blockIdx.x * 256 + threadIdx.x;
    int t = e & 4095;
    int rest = e >> 12;
    int j = rest % 36;
    int b = rest / 36;
    float v = x[(size_t)b * D_ * T_ + (size_t)(SEM_DIM + j) * T_ + t];
    float a = tanhf(v);
    float code = rintf((a + 1.0f) * 10.0f);
    out[(size_t)b * NCH * T_ + (size_t)(1 + j) * T_ + t] = code;
    out[RECON_OFF + (size_t)b * D_ * T_ + (size_t)(SEM_DIM + j) * T_ + t]
        = code * 0.1f - 1.0f;
}

// ---- kernel 6: recon sem gather ----
__global__ __launch_bounds__(256) void gather_kernel(
    const float* __restrict__ es, const float* __restrict__ cu,
    const float* __restrict__ codes, float* __restrict__ out)
{
    int bid = blockIdx.x;
    int b  = bid >> 6;
    int tc = bid & 63;
    int t  = tc * 64 + (threadIdx.x & 63);
    int w  = threadIdx.x >> 6;

    int c = (int)codes[(size_t)b * NCH * T_ + t];
    float denom = fmaxf(cu[c], EPSV);
    const float* erow = es + (size_t)c * SEM_DIM;
    float* orow = out + RECON_OFF + (size_t)b * D_ * T_ + t;

    #pragma unroll
    for (int i = 0; i < 16; i++) {
        int d = w * 64 + i * 4;
        float4 ev = *(const float4*)(erow + d);
        orow[(size_t)(d + 0) * T_] = ev.x / denom;
        orow[(size_t)(d + 1) * T_] = ev.y / denom;
        orow[(size_t)(d + 2) * T_] = ev.z / denom;
        orow[(size_t)(d + 3) * T_] = ev.w / denom;
    }
}

extern "C" void kernel_launch(void* const* d_in, const int* in_sizes, int n_in,
                              void* d_out, int out_size, void* d_ws, size_t ws_size,
                              hipStream_t stream)
{
    const float* x  = (const float*)d_in[0];
    const float* es = (const float*)d_in[1];
    const float* cu = (const float*)d_in[2];
    float* out = (float*)d_out;

    u16*   Xh   = (u16*)(out + OFF_XH);
    u16*   Xl   = (u16*)(out + OFF_XL);
    u16*   Eh   = (u16*)(out + OFF_EH);
    u16*   El   = (u16*)(out + OFF_EL);
    float* e2   = out + OFF_E2;
    u64*   amin = (u64*)(out + OFF_AMIN);
    int*   cnt  = (int*)(out + OFF_CNT);

    // candidate list: use d_ws (bigger cap) if it is large enough
    size_t need = (size_t)ROWS * CAPMAX * sizeof(u16);
    int  cap   = (ws_size >= need) ? CAPMAX : CAPFALL;
    u16* cand  = (ws_size >= need) ? (u16*)d_ws : (u16*)(out + OFF_CAND);

    init_kernel<<<ROWS / 256, 256, 0, stream>>>(amin, cnt);
    prep_emb_kernel<<<CODEBOOK, 256, 0, stream>>>(es, cu, Eh, El, e2);
    prep_x_kernel<<<B_ * 64 * 4, 256, 0, stream>>>(x, Xh, Xl);

    dim3 g(ROWS / GBM, NS);
    gemm_emit_kernel<<<g, 512, 0, stream>>>(Xh, Xl, Eh, El, e2, amin, cnt, cand, cap);

    finalize_kernel<<<ROWS / 4, 256, 0, stream>>>(cnt, cand, amin, x, es, cu, e2, out, cap);

    fsq_kernel<<<(B_ * 36 * T_) / 256, 256, 0, stream>>>(x, out);

    gather_kernel<<<B_ * (T_ / 64), 256, 0, stream>>>(es, cu, out, out);
}

// Round 6
// 1031.275 us; speedup vs baseline: 3.9429x; 1.4487x over previous
//
#include <hip/hip_runtime.h>
#include <hip/hip_bf16.h>

// ---- problem constants ----
#define SEM_DIM   256
#define CODEBOOK  8192
#define B_        8
#define T_        4096
#define D_        292
#define NCH       37
#define EPSV      1e-5f
#define NS        2
#define DELTA     0.03f
#define CAPMAX    24
#define CAPFALL   11

typedef unsigned short u16;
typedef unsigned long long u64;
typedef float v4f __attribute__((ext_vector_type(4)));
typedef short v8s __attribute__((ext_vector_type(8)));

constexpr int ROWS = B_ * T_;                 // 32768
// d_out used as flat scratch until the final writers run. Aliasing order:
// gemm reads Xh/Xl/Eh/El -> finalize reads e2/amin/cnt/cand and writes sem
// codes -> fsq writes ac codes + ac recon -> gather overwrites sem recon
// (which hosts Eh/El/e2/amin/cnt/cand, all dead by then).
constexpr size_t OFF_XH   = 0;                // u16[32768*256] = 4,194,304 fl
constexpr size_t OFF_XL   = 4194304;
constexpr size_t OFF_EH   = 8388608;          // u16[8192*256] = 1,048,576 fl
constexpr size_t OFF_EL   = 9437184;
constexpr size_t OFF_E2   = 10485760;         // f32[8192] -> 10,493,952
constexpr size_t OFF_AMIN = 10493952;         // u64[32768] -> 10,559,488
constexpr size_t OFF_CNT  = 10559488;         // i32[32768] -> 10,592,256
constexpr size_t OFF_CAND = 10592256;         // u16[32768*11] -> 10,772,480
constexpr size_t RECON_OFF = 1212416;

__device__ __forceinline__ u16 bf16bits(float v) {
    __hip_bfloat16 h = __float2bfloat16(v);
    return *(u16*)&h;
}
__device__ __forceinline__ float bf16val(u16 b) {
    __hip_bfloat16 h; *(u16*)&h = b; return __bfloat162float(h);
}
__device__ __forceinline__ unsigned enc_f(float f) {
    unsigned u = __float_as_uint(f);
    return (u & 0x80000000u) ? ~u : (u | 0x80000000u);
}

// ---- kernel 0: init amin/cnt ----
__global__ __launch_bounds__(256) void init_kernel(u64* __restrict__ amin,
                                                   int* __restrict__ cnt)
{
    int r = blockIdx.x * 256 + threadIdx.x;
    amin[r] = 0xFFFFFFFFFFFFFFFFull;
    cnt[r] = 0;
}

// ---- kernel 1: Eh/El = split-bf16(es/max(cu,eps)); e2 = sum(emb^2) ----
__global__ __launch_bounds__(256) void prep_emb_kernel(
    const float* __restrict__ es, const float* __restrict__ cu,
    u16* __restrict__ Eh, u16* __restrict__ El, float* __restrict__ e2)
{
    int c = blockIdx.x;
    int d = threadIdx.x;
    float denom = fmaxf(cu[c], EPSV);
    float v = es[(size_t)c * SEM_DIM + d] / denom;   // IEEE div, matches ref
    u16 hb = bf16bits(v);
    float rr = v - bf16val(hb);
    Eh[(size_t)c * SEM_DIM + d] = hb;
    El[(size_t)c * SEM_DIM + d] = bf16bits(rr);

    float s = v * v;
    #pragma unroll
    for (int m = 32; m >= 1; m >>= 1) s += __shfl_xor(s, m);
    __shared__ float red[4];
    int lane = threadIdx.x & 63, w = threadIdx.x >> 6;
    if (lane == 0) red[w] = s;
    __syncthreads();
    if (threadIdx.x == 0)
        e2[c] = red[0] + red[1] + red[2] + red[3];
}

// ---- kernel 2: transpose-cast x[:, :256, :] -> Xh, Xl row-major (m,k) ----
__global__ __launch_bounds__(256) void prep_x_kernel(
    const float* __restrict__ x, u16* __restrict__ Xh, u16* __restrict__ Xl)
{
    __shared__ float tile[64][65];
    int bidx = blockIdx.x;            // 8 * 64 * 4
    int dc = bidx & 3;
    int tc = (bidx >> 2) & 63;
    int b  = bidx >> 8;
    int d0 = dc * 64, t0 = tc * 64;
    int tx = threadIdx.x & 63;
    int dq = threadIdx.x >> 6;
    #pragma unroll
    for (int i = 0; i < 16; i++) {
        int d = dq * 16 + i;
        tile[d][tx] = x[((size_t)b * D_ + d0 + d) * T_ + t0 + tx];
    }
    __syncthreads();
    #pragma unroll
    for (int j = 0; j < 2; j++) {
        int lin = threadIdx.x * 2 + j;      // 0..511
        int tr  = lin >> 3;
        int ch  = lin & 7;
        unsigned hw[4], lw[4];
        #pragma unroll
        for (int p = 0; p < 4; p++) {
            float v0 = tile[ch * 8 + p * 2 + 0][tr];
            float v1 = tile[ch * 8 + p * 2 + 1][tr];
            u16 h0 = bf16bits(v0), h1 = bf16bits(v1);
            u16 l0 = bf16bits(v0 - bf16val(h0));
            u16 l1 = bf16bits(v1 - bf16val(h1));
            hw[p] = (unsigned)h0 | ((unsigned)h1 << 16);
            lw[p] = (unsigned)l0 | ((unsigned)l1 << 16);
        }
        size_t off = ((size_t)b * T_ + t0 + tr) * SEM_DIM + d0 + ch * 8;
        *(uint4*)(Xh + off) = make_uint4(hw[0], hw[1], hw[2], hw[3]);
        *(uint4*)(Xl + off) = make_uint4(lw[0], lw[1], lw[2], lw[3]);
    }
}

// ---- kernel 3: single-pass MFMA GEMM, A resident in VGPRs (all indices
//      compile-time: sub fully unrolled -> no scratch demotion), B streamed
//      via double-buffered swizzled LDS; running-min threshold emission. ----
#define GBM 64
#define GBN 64
#define NTILES (CODEBOOK / NS / GBN)          // 64

__global__ __launch_bounds__(256, 2) void gemm_emit_kernel(
    const u16* __restrict__ Xh, const u16* __restrict__ Xl,
    const u16* __restrict__ Eh, const u16* __restrict__ El,
    const float* __restrict__ e2,
    u64* __restrict__ amin, int* __restrict__ cnt, u16* __restrict__ cand,
    int cap)
{
    __shared__ u16 Bs[2][2][GBN * 64];        // [parity][Eh/El][64n x 64k] = 32 KB
    int tid  = threadIdx.x;
    int lane = tid & 63, wid = tid >> 6;
    int wm = wid >> 1, wn = wid & 1;          // 2x2 waves; wave tile 32m x 32n
    int l15 = lane & 15, l4 = lane >> 4;
    int m0 = blockIdx.x * GBM;
    int cbase = blockIdx.y * (CODEBOOK / NS);

    // A fragments resident in VGPRs (all compile-time indexed)
    v8s aXh[2][8], aXl[2][8];
    #pragma unroll
    for (int mf = 0; mf < 2; mf++) {
        int row = m0 + wm * 32 + mf * 16 + l15;
        #pragma unroll
        for (int kk = 0; kk < 8; kk++) {
            size_t off = (size_t)row * SEM_DIM + (kk * 4 + l4) * 8;
            aXh[mf][kk] = *(const v8s*)(Xh + off);
            aXl[mf][kk] = *(const v8s*)(Xl + off);
        }
    }

    // staging: 256 threads x 4 x 16B slots = 16 KB (Eh 64x64 + El 64x64)
    int sn0 = tid >> 3;                       // 0..31
    int sc  = tid & 7;                        // chunk
    int wofs0 = sn0 * 64 + ((sc ^ (sn0 & 7)) * 8);
    int wofs1 = (sn0 + 32) * 64 + ((sc ^ ((sn0 + 32) & 7)) * 8);
    uint4 sA, sB, sC, sD;

    auto load_stage = [&](int nt, int sub) {
        int n0 = cbase + nt * GBN, k0 = sub * 64;
        size_t ra = (size_t)(n0 + sn0) * SEM_DIM + k0 + sc * 8;
        size_t rb = (size_t)(n0 + sn0 + 32) * SEM_DIM + k0 + sc * 8;
        sA = *(const uint4*)(Eh + ra);
        sB = *(const uint4*)(Eh + rb);
        sC = *(const uint4*)(El + ra);
        sD = *(const uint4*)(El + rb);
    };

    v4f acc[2][2];
    #pragma unroll
    for (int mf = 0; mf < 2; mf++)
        #pragma unroll
        for (int nf = 0; nf < 2; nf++)
            acc[mf][nf] = (v4f){0.f, 0.f, 0.f, 0.f};

    float rv[8]; int ri[8];
    #pragma unroll
    for (int s = 0; s < 8; s++) { rv[s] = 3.4e38f; ri[s] = 0; }

    load_stage(0, 0);

    for (int nt = 0; nt < NTILES; ++nt) {
        int n0 = cbase + nt * GBN;
        #pragma unroll
        for (int sub = 0; sub < 4; ++sub) {          // fully unrolled: sub is a constant
            const int p = sub & 1;                   // 4*nt even -> parity == sub&1
            *(uint4*)&Bs[p][0][wofs0] = sA;
            *(uint4*)&Bs[p][0][wofs1] = sB;
            *(uint4*)&Bs[p][1][wofs0] = sC;
            *(uint4*)&Bs[p][1][wofs1] = sD;
            __syncthreads();
            if (sub < 3) load_stage(nt, sub + 1);
            else if (nt + 1 < NTILES) load_stage(nt + 1, 0);

            #pragma unroll
            for (int w = 0; w < 2; w++) {
                v8s bh[2], bl[2];
                #pragma unroll
                for (int nf = 0; nf < 2; nf++) {
                    int n = wn * 32 + nf * 16 + l15;
                    int c = w * 4 + l4;
                    int e = n * 64 + ((c ^ (n & 7)) * 8);
                    bh[nf] = *(const v8s*)&Bs[p][0][e];
                    bl[nf] = *(const v8s*)&Bs[p][1][e];
                }
                #pragma unroll
                for (int mf = 0; mf < 2; mf++)
                    #pragma unroll
                    for (int nf = 0; nf < 2; nf++) {
                        acc[mf][nf] = __builtin_amdgcn_mfma_f32_16x16x32_bf16(
                            aXh[mf][sub * 2 + w], bh[nf], acc[mf][nf], 0, 0, 0);
                        acc[mf][nf] = __builtin_amdgcn_mfma_f32_16x16x32_bf16(
                            aXl[mf][sub * 2 + w], bh[nf], acc[mf][nf], 0, 0, 0);
                        acc[mf][nf] = __builtin_amdgcn_mfma_f32_16x16x32_bf16(
                            aXh[mf][sub * 2 + w], bl[nf], acc[mf][nf], 0, 0, 0);
                    }
            }

            if (sub == 3) {
                // epilogue: scores, running-min, threshold emit
                int cc0 = n0 + wn * 32 + l15, cc1 = cc0 + 16;
                float e20 = e2[cc0], e21 = e2[cc1];
                #pragma unroll
                for (int mf = 0; mf < 2; mf++)
                    #pragma unroll
                    for (int r = 0; r < 4; r++) {
                        int slot = mf * 4 + r;
                        float s0 = fmaf(-2.0f, acc[mf][0][r], e20);
                        float s1 = fmaf(-2.0f, acc[mf][1][r], e21);
                        float v; int i;
                        if (s1 < s0) { v = s1; i = cc1; } else { v = s0; i = cc0; }
                        #pragma unroll
                        for (int m = 1; m < 16; m <<= 1) {
                            float ov = __shfl_xor(v, m);
                            int   oi = __shfl_xor(i, m);
                            if (ov < v || (ov == v && oi < i)) { v = ov; i = oi; }
                        }
                        if (v < rv[slot] || (v == rv[slot] && i < ri[slot])) {
                            rv[slot] = v; ri[slot] = i;
                        }
                        float thr = rv[slot] + DELTA;
                        int row = m0 + wm * 32 + mf * 16 + l4 * 4 + r;
                        if (s0 <= thr) {
                            int q = atomicAdd(&cnt[row], 1);
                            if (q < cap) cand[(size_t)row * cap + q] = (u16)cc0;
                        }
                        if (s1 <= thr) {
                            int q = atomicAdd(&cnt[row], 1);
                            if (q < cap) cand[(size_t)row * cap + q] = (u16)cc1;
                        }
                        acc[mf][0][r] = 0.f;
                        acc[mf][1][r] = 0.f;
                    }
            }
        }
    }

    // per-row approx-argmin guard (overflow safety)
    #pragma unroll
    for (int slot = 0; slot < 8; slot++) {
        if (l15 == 0) {
            int row = m0 + wm * 32 + (slot >> 2) * 16 + l4 * 4 + (slot & 3);
            u64 key = ((u64)enc_f(rv[slot]) << 32) | (unsigned)ri[slot];
            atomicMin(&amin[row], key);
        }
    }
}

// ---- kernel 4: exact fp32 rescore of candidates, wave-per-row ----
__global__ __launch_bounds__(256) void finalize_kernel(
    const int* __restrict__ cnt, const u16* __restrict__ cand,
    const u64* __restrict__ amin,
    const float* __restrict__ x, const float* __restrict__ es,
    const float* __restrict__ cu, const float* __restrict__ e2,
    float* __restrict__ out, int cap)
{
    int r = (blockIdx.x * 256 + threadIdx.x) >> 6;   // one wave per row
    int lane = threadIdx.x & 63;
    int b = r >> 12, t = r & 4095;

    float xv[4];
    #pragma unroll
    for (int j = 0; j < 4; j++)
        xv[j] = x[((size_t)b * D_ + lane + j * 64) * T_ + t];

    int n = cnt[r]; if (n > cap) n = cap;
    int ai = (int)(unsigned)(amin[r] & 0xFFFFFFFFu);

    float best_s = 3.4e38f; int best_i = 0x7FFFFFFF;
    for (int p = 0; p <= n; p++) {
        int c = (p < n) ? (int)cand[(size_t)r * cap + p] : ai;
        float den = fmaxf(cu[c], EPSV);
        float partial = 0.f;
        #pragma unroll
        for (int j = 0; j < 4; j++)
            partial = fmaf(xv[j], es[(size_t)c * SEM_DIM + lane + j * 64] / den, partial);
        #pragma unroll
        for (int m = 32; m >= 1; m >>= 1) partial += __shfl_xor(partial, m);
        float sc = e2[c] - 2.0f * partial;
        if (sc < best_s || (sc == best_s && c < best_i)) { best_s = sc; best_i = c; }
    }
    if (lane == 0) out[(size_t)b * NCH * T_ + t] = (float)best_i;
}

// ---- kernel 5: FSQ codes + ac recon ----
__global__ __launch_bounds__(256) void fsq_kernel(
    const float* __restrict__ x, float* __restrict__ out)
{
    int e = blockIdx.x * 256 + threadIdx.x;
    int t = e & 4095;
    int rest = e >> 12;
    int j = rest % 36;
    int b = rest / 36;
    float v = x[(size_t)b * D_ * T_ + (size_t)(SEM_DIM + j) * T_ + t];
    float a = tanhf(v);
    float code = rintf((a + 1.0f) * 10.0f);
    out[(size_t)b * NCH * T_ + (size_t)(1 + j) * T_ + t] = code;
    out[RECON_OFF + (size_t)b * D_ * T_ + (size_t)(SEM_DIM + j) * T_ + t]
        = code * 0.1f - 1.0f;
}

// ---- kernel 6: recon sem gather ----
__global__ __launch_bounds__(256) void gather_kernel(
    const float* __restrict__ es, const float* __restrict__ cu,
    const float* __restrict__ codes, float* __restrict__ out)
{
    int bid = blockIdx.x;
    int b  = bid >> 6;
    int tc = bid & 63;
    int t  = tc * 64 + (threadIdx.x & 63);
    int w  = threadIdx.x >> 6;

    int c = (int)codes[(size_t)b * NCH * T_ + t];
    float denom = fmaxf(cu[c], EPSV);
    const float* erow = es + (size_t)c * SEM_DIM;
    float* orow = out + RECON_OFF + (size_t)b * D_ * T_ + t;

    #pragma unroll
    for (int i = 0; i < 16; i++) {
        int d = w * 64 + i * 4;
        float4 ev = *(const float4*)(erow + d);
        orow[(size_t)(d + 0) * T_] = ev.x / denom;
        orow[(size_t)(d + 1) * T_] = ev.y / denom;
        orow[(size_t)(d + 2) * T_] = ev.z / denom;
        orow[(size_t)(d + 3) * T_] = ev.w / denom;
    }
}

extern "C" void kernel_launch(void* const* d_in, const int* in_sizes, int n_in,
                              void* d_out, int out_size, void* d_ws, size_t ws_size,
                              hipStream_t stream)
{
    const float* x  = (const float*)d_in[0];
    const float* es = (const float*)d_in[1];
    const float* cu = (const float*)d_in[2];
    float* out = (float*)d_out;

    u16*   Xh   = (u16*)(out + OFF_XH);
    u16*   Xl   = (u16*)(out + OFF_XL);
    u16*   Eh   = (u16*)(out + OFF_EH);
    u16*   El   = (u16*)(out + OFF_EL);
    float* e2   = out + OFF_E2;
    u64*   amin = (u64*)(out + OFF_AMIN);
    int*   cnt  = (int*)(out + OFF_CNT);

    size_t need = (size_t)ROWS * CAPMAX * sizeof(u16);
    int  cap   = (ws_size >= need) ? CAPMAX : CAPFALL;
    u16* cand  = (ws_size >= need) ? (u16*)d_ws : (u16*)(out + OFF_CAND);

    init_kernel<<<ROWS / 256, 256, 0, stream>>>(amin, cnt);
    prep_emb_kernel<<<CODEBOOK, 256, 0, stream>>>(es, cu, Eh, El, e2);
    prep_x_kernel<<<B_ * 64 * 4, 256, 0, stream>>>(x, Xh, Xl);

    dim3 g(ROWS / GBM, NS);
    gemm_emit_kernel<<<g, 256, 0, stream>>>(Xh, Xl, Eh, El, e2, amin, cnt, cand, cap);

    finalize_kernel<<<ROWS / 4, 256, 0, stream>>>(cnt, cand, amin, x, es, cu, e2, out, cap);

    fsq_kernel<<<(B_ * 36 * T_) / 256, 256, 0, stream>>>(x, out);

    gather_kernel<<<B_ * (T_ / 64), 256, 0, stream>>>(es, cu, out, out);
}